// Round 9
// baseline (1054.881 us; speedup 1.0000x reference)
//
#include <hip/hip_runtime.h>
#include <float.h>

#define NN 100000
#define NE 1600000
#define NH 128
#define N_MID 9
#define NBKT ((NN + 255) / 256)      // 391 dst-buckets of 256 nodes
#define P1_EPB 4096                  // edges per pass-1 block
#define NP1B ((NE + P1_EPB - 1) / P1_EPB)  // 391 pass-1 blocks
#define P2_CAP 5120                  // LDS record capacity in pass 2 (avg 4092, sigma 64)

typedef _Float16 half8 __attribute__((ext_vector_type(8)));
typedef _Float16 half2v __attribute__((ext_vector_type(2)));
typedef float f32x4 __attribute__((ext_vector_type(4)));

// ---------------- dtype prep ----------------

__global__ __launch_bounds__(256) void conv_x(const float* __restrict__ in, _Float16* __restrict__ out) {
    int i = blockIdx.x * 256 + threadIdx.x;
    if (i >= NN * NH / 8) return;
    float4 v0 = ((const float4*)in)[i * 2];
    float4 v1 = ((const float4*)in)[i * 2 + 1];
    half8 o;
    o[0] = (_Float16)v0.x; o[1] = (_Float16)v0.y; o[2] = (_Float16)v0.z; o[3] = (_Float16)v0.w;
    o[4] = (_Float16)v1.x; o[5] = (_Float16)v1.y; o[6] = (_Float16)v1.z; o[7] = (_Float16)v1.w;
    ((half8*)out)[i] = o;
}

// Wt16[l][n][k] = (f16)(16 * W[l][k][n])   (transposed, pre-scaled: pairs with (A.X)/16)
__global__ __launch_bounds__(256) void conv_w(const float* __restrict__ W, _Float16* __restrict__ Wt) {
    int i = blockIdx.x * 256 + threadIdx.x;
    if (i >= N_MID * NH * NH) return;
    int l = i / (NH * NH), rem = i % (NH * NH);
    int n = rem / NH, k = rem % NH;
    Wt[i] = (_Float16)(16.0f * W[l * NH * NH + k * NH + n]);
}

// ---------------- edge sort: atomic-free bucket pipeline ----------------

__global__ __launch_bounds__(256) void bhist_k(const int* __restrict__ edst, int* __restrict__ bh) {
    __shared__ int hist[NBKT];
    const int tid = threadIdx.x;
    for (int i = tid; i < NBKT; i += 256) hist[i] = 0;
    __syncthreads();
    const int e0 = blockIdx.x * P1_EPB;
    const int e1 = min(e0 + P1_EPB, NE);
    for (int e = e0 + tid; e < e1; e += 256) atomicAdd(&hist[edst[e] >> 8], 1);
    __syncthreads();
    for (int i = tid; i < NBKT; i += 256) bh[blockIdx.x * NBKT + i] = hist[i];
}

__global__ __launch_bounds__(512) void bscan_cols(const int* __restrict__ bh, int* __restrict__ obh,
                                                  int* __restrict__ btot) {
    __shared__ int s[512];
    const int b = blockIdx.x, tid = threadIdx.x;
    int v = (tid < NP1B) ? bh[tid * NBKT + b] : 0;
    s[tid] = v;
    __syncthreads();
    for (int off = 1; off < 512; off <<= 1) {
        int t = (tid >= off) ? s[tid - off] : 0;
        __syncthreads();
        s[tid] += t;
        __syncthreads();
    }
    if (tid < NP1B) obh[tid * NBKT + b] = s[tid] - v;
    if (tid == NP1B - 1) btot[b] = s[tid];
}

__global__ __launch_bounds__(512) void bscan_top(const int* __restrict__ btot, int* __restrict__ bbase) {
    __shared__ int s[512];
    const int tid = threadIdx.x;
    int v = (tid < NBKT) ? btot[tid] : 0;
    s[tid] = v;
    __syncthreads();
    for (int off = 1; off < 512; off <<= 1) {
        int t = (tid >= off) ? s[tid - off] : 0;
        __syncthreads();
        s[tid] += t;
        __syncthreads();
    }
    if (tid < NBKT) bbase[tid] = s[tid] - v;
    if (tid == NBKT - 1) bbase[NBKT] = s[tid];   // == NE
}

__global__ __launch_bounds__(256) void p1_bucket(const int* __restrict__ esrc, const int* __restrict__ edst,
                                                 const float* __restrict__ av, const int* __restrict__ bbase,
                                                 const int* __restrict__ obh, int2* __restrict__ gbuf) {
    __shared__ int base[NBKT];
    __shared__ int rnk[NBKT];
    const int tid = threadIdx.x;
    for (int i = tid; i < NBKT; i += 256) {
        base[i] = bbase[i] + obh[blockIdx.x * NBKT + i];
        rnk[i] = 0;
    }
    __syncthreads();
    const int e0 = blockIdx.x * P1_EPB;
    const int e1 = min(e0 + P1_EPB, NE);
    for (int e = e0 + tid; e < e1; e += 256) {
        int d = edst[e];
        int b = d >> 8;
        int r = atomicAdd(&rnk[b], 1);
        gbuf[base[b] + r] = make_int2(esrc[e] | ((d & 255) << 24), __float_as_int(av[e]));
    }
}

__global__ __launch_bounds__(256) void p2_sort(const int2* __restrict__ gbuf, const int* __restrict__ bbase,
                                               int* __restrict__ rp, int2* __restrict__ rec) {
    __shared__ int hist[256];
    __shared__ int sc[256];
    __shared__ int offs[256];
    __shared__ int r2[256];
    __shared__ int2 buf[P2_CAP];
    const int b = blockIdx.x;
    const int tid = threadIdx.x;
    const int n0 = b * 256;
    const int e0 = bbase[b];
    const int e1 = bbase[b + 1];
    const int n = e1 - e0;
    hist[tid] = 0; r2[tid] = 0;
    __syncthreads();
    for (int i = tid; i < n; i += 256) atomicAdd(&hist[(unsigned)gbuf[e0 + i].x >> 24], 1);
    __syncthreads();
    sc[tid] = hist[tid];
    __syncthreads();
    for (int off = 1; off < 256; off <<= 1) {
        int t = (tid >= off) ? sc[tid - off] : 0;
        __syncthreads();
        sc[tid] += t;
        __syncthreads();
    }
    offs[tid] = sc[tid] - hist[tid];
    __syncthreads();
    if (n0 + tid < NN) rp[n0 + tid] = e0 + offs[tid];
    if (b == NBKT - 1 && tid == 0) rp[NN] = e1;
    if (n <= P2_CAP) {
        for (int i = tid; i < n; i += 256) {
            int2 rv = gbuf[e0 + i];
            int dl = (unsigned)rv.x >> 24;
            int p = offs[dl] + atomicAdd(&r2[dl], 1);
            buf[p] = make_int2(rv.x & 0x00FFFFFF, rv.y);
        }
        __syncthreads();
        for (int i = tid; i < n; i += 256) rec[e0 + i] = buf[i];
    } else {
        for (int i = tid; i < n; i += 256) {
            int2 rv = gbuf[e0 + i];
            int dl = (unsigned)rv.x >> 24;
            int p = offs[dl] + atomicAdd(&r2[dl], 1);
            rec[e0 + p] = make_int2(rv.x & 0x00FFFFFF, rv.y);
        }
    }
}

// ---------------- fused layer: Xo = relu((A @ X) @ W + b) ----------------
// Phase 1: 16 groups of 16 lanes each gather 4 dst-node rows (A@X), f32 acc,
//          store (A@X)/16 as f16 into LDS tile (64 x 136-padded).
// Phase 2: per-wave 16x128 MFMA of tile with Wt16 (= 16*W^T, global; L1/L2 broadcast),
//          add bias, relu, store f16.

__global__ __launch_bounds__(256) void layer_fused(const _Float16* __restrict__ X, const _Float16* __restrict__ Wt16,
                                                   const int2* __restrict__ rec, const int* __restrict__ rp,
                                                   const float* __restrict__ bias, _Float16* __restrict__ Xo) {
    __shared__ _Float16 xs[64 * 136];
    const int tid = threadIdx.x;
    const int wid = tid >> 6;
    const int lane = tid & 63;
    const int g = lane >> 4;
    const int c = lane & 15;          // 8-col block owner within group
    const int gid = wid * 4 + g;      // 0..15
    const int node0 = blockIdx.x * 64;

    // ---- phase 1: gather ----
    for (int q = 0; q < 4; q++) {
        const int nl = gid * 4 + q;
        const int node = node0 + nl;
        int beg = 0, end = 0;
        if (node < NN) { beg = rp[node]; end = rp[node + 1]; }
        float acc[8] = {0.f, 0.f, 0.f, 0.f, 0.f, 0.f, 0.f, 0.f};
        float acc2[8] = {0.f, 0.f, 0.f, 0.f, 0.f, 0.f, 0.f, 0.f};
        int e = beg;
        for (; e + 1 < end; e += 2) {
            int2 rv1 = rec[e];
            int2 rv2 = rec[e + 1];
            half8 r1 = *(const half8*)&X[(size_t)rv1.x * NH + c * 8];
            half8 r2 = *(const half8*)&X[(size_t)rv2.x * NH + c * 8];
            float v1 = __int_as_float(rv1.y);
            float v2 = __int_as_float(rv2.y);
#pragma unroll
            for (int j = 0; j < 8; j++) {
                acc[j]  = fmaf(v1, (float)r1[j], acc[j]);
                acc2[j] = fmaf(v2, (float)r2[j], acc2[j]);
            }
        }
        if (e < end) {
            int2 rv = rec[e];
            float v = __int_as_float(rv.y);
            half8 r1 = *(const half8*)&X[(size_t)rv.x * NH + c * 8];
#pragma unroll
            for (int j = 0; j < 8; j++) acc[j] = fmaf(v, (float)r1[j], acc[j]);
        }
        half8 o;
#pragma unroll
        for (int j = 0; j < 8; j++) o[j] = (_Float16)((acc[j] + acc2[j]) * 0.0625f);
        *(half8*)&xs[nl * 136 + c * 8] = o;
    }
    __syncthreads();

    // ---- phase 2: MFMA ----
    const int r = lane & 15, kb = lane >> 4;
    const _Float16* ap = xs + (wid * 16 + r) * 136 + kb * 8;
    half8 a0 = *(const half8*)(ap);
    half8 a1 = *(const half8*)(ap + 32);
    half8 a2 = *(const half8*)(ap + 64);
    half8 a3 = *(const half8*)(ap + 96);
    f32x4 acc[8];
#pragma unroll
    for (int t = 0; t < 8; t++) acc[t] = (f32x4){0.f, 0.f, 0.f, 0.f};
#pragma unroll
    for (int t = 0; t < 8; t++) {
        const _Float16* wp = Wt16 + (size_t)(16 * t + r) * NH + kb * 8;
        half8 b0 = *(const half8*)(wp);
        half8 b1 = *(const half8*)(wp + 32);
        half8 b2 = *(const half8*)(wp + 64);
        half8 b3 = *(const half8*)(wp + 96);
        acc[t] = __builtin_amdgcn_mfma_f32_16x16x32_f16(a0, b0, acc[t], 0, 0, 0);
        acc[t] = __builtin_amdgcn_mfma_f32_16x16x32_f16(a1, b1, acc[t], 0, 0, 0);
        acc[t] = __builtin_amdgcn_mfma_f32_16x16x32_f16(a2, b2, acc[t], 0, 0, 0);
        acc[t] = __builtin_amdgcn_mfma_f32_16x16x32_f16(a3, b3, acc[t], 0, 0, 0);
    }
    float bb[8];
#pragma unroll
    for (int t = 0; t < 8; t++) bb[t] = bias[16 * t + r];
    const int orow = wid * 16 + kb * 4;
#pragma unroll
    for (int j = 0; j < 4; j++) {
        int nr = node0 + orow + j;
        if (nr < NN) {
            _Float16* op = Xo + (size_t)nr * NH + r;
#pragma unroll
            for (int t = 0; t < 8; t++) op[16 * t] = (_Float16)fmaxf(acc[t][j] + bb[t], 0.f);
        }
    }
}

// ---------------- layer 10 ----------------

__global__ __launch_bounds__(256) void dot128_f16(const _Float16* __restrict__ X, const float* __restrict__ w,
                                                  float* __restrict__ s10) {
    int node = blockIdx.x * 4 + (threadIdx.x >> 6);
    if (node >= NN) return;
    int lane = threadIdx.x & 63;
    half2v xv = *(const half2v*)&X[(size_t)node * NH + lane * 2];
    float2 wv = *(const float2*)&w[lane * 2];
    float p = (float)xv[0] * wv.x + (float)xv[1] * wv.y;
#pragma unroll
    for (int off = 32; off; off >>= 1) p += __shfl_down(p, off, 64);
    if (lane == 0) s10[node] = p;
}

__global__ __launch_bounds__(256) void spmm_scalar(const float* __restrict__ s10, const int2* __restrict__ rec,
                                                   const int* __restrict__ rp, const float* __restrict__ b10,
                                                   float* __restrict__ o10) {
    int node = blockIdx.x * 256 + threadIdx.x;
    if (node >= NN) return;
    int beg = rp[node], end = rp[node + 1];
    float a = 0.f;
    for (int e = beg; e < end; e++) {
        int2 r = rec[e];
        a = fmaf(__int_as_float(r.y), s10[r.x], a);
    }
    o10[node] = a + b10[0];
}

// ---------------- log_softmax ----------------

#define LSM_NB 240

__global__ __launch_bounds__(256) void lsm_max(const float* __restrict__ v, float* __restrict__ pmax) {
    __shared__ float s[256];
    float m = -FLT_MAX;
    for (int i = blockIdx.x * 256 + threadIdx.x; i < NN; i += LSM_NB * 256) m = fmaxf(m, v[i]);
    s[threadIdx.x] = m;
    __syncthreads();
    for (int off = 128; off; off >>= 1) {
        if (threadIdx.x < off) s[threadIdx.x] = fmaxf(s[threadIdx.x], s[threadIdx.x + off]);
        __syncthreads();
    }
    if (threadIdx.x == 0) pmax[blockIdx.x] = s[0];
}

__global__ __launch_bounds__(256) void lsm_sum(const float* __restrict__ v, const float* __restrict__ pmax,
                                               float* __restrict__ psum) {
    __shared__ float s[256];
    float m = -FLT_MAX;
    if (threadIdx.x < LSM_NB) m = pmax[threadIdx.x];
    s[threadIdx.x] = m;
    __syncthreads();
    for (int off = 128; off; off >>= 1) {
        if (threadIdx.x < off) s[threadIdx.x] = fmaxf(s[threadIdx.x], s[threadIdx.x + off]);
        __syncthreads();
    }
    float gm = s[0];
    __syncthreads();
    float sum = 0.f;
    for (int i = blockIdx.x * 256 + threadIdx.x; i < NN; i += LSM_NB * 256) sum += expf(v[i] - gm);
    s[threadIdx.x] = sum;
    __syncthreads();
    for (int off = 128; off; off >>= 1) {
        if (threadIdx.x < off) s[threadIdx.x] += s[threadIdx.x + off];
        __syncthreads();
    }
    if (threadIdx.x == 0) psum[blockIdx.x] = s[0];
}

__global__ __launch_bounds__(256) void lsm_fin(const float* __restrict__ pmax, const float* __restrict__ psum,
                                               float* __restrict__ c) {
    __shared__ float s[256];
    float m = -FLT_MAX, sum = 0.f;
    if (threadIdx.x < LSM_NB) { m = pmax[threadIdx.x]; sum = psum[threadIdx.x]; }
    s[threadIdx.x] = m;
    __syncthreads();
    for (int off = 128; off; off >>= 1) {
        if (threadIdx.x < off) s[threadIdx.x] = fmaxf(s[threadIdx.x], s[threadIdx.x + off]);
        __syncthreads();
    }
    float gm = s[0];
    __syncthreads();
    s[threadIdx.x] = sum;
    __syncthreads();
    for (int off = 128; off; off >>= 1) {
        if (threadIdx.x < off) s[threadIdx.x] += s[threadIdx.x + off];
        __syncthreads();
    }
    if (threadIdx.x == 0) c[0] = gm + logf(s[0]);
}

__global__ __launch_bounds__(256) void lsm_write(const float* __restrict__ o10, const float* __restrict__ c,
                                                 float* __restrict__ out) {
    int i = blockIdx.x * 256 + threadIdx.x;
    if (i < NN) out[i] = o10[i] - c[0];
}

// ---------------- launch ----------------

extern "C" void kernel_launch(void* const* d_in, const int* in_sizes, int n_in,
                              void* d_out, int out_size, void* d_ws, size_t ws_size,
                              hipStream_t stream) {
    const float* features = (const float*)d_in[0];
    const float* adj_vals = (const float*)d_in[1];
    const float* Ws       = (const float*)d_in[2];
    const float* bs       = (const float*)d_in[3];
    const float* W10      = (const float*)d_in[4];
    const float* b10      = (const float*)d_in[5];
    const int*   esrc     = (const int*)d_in[6];
    const int*   edst     = (const int*)d_in[7];
    float* out = (float*)d_out;

    char* ws = (char*)d_ws;
    const size_t SZH = (size_t)NN * NH * 2;          // 25.6 MB per f16 buffer
    _Float16* xA  = (_Float16*)(ws);
    _Float16* xB  = (_Float16*)(ws + SZH);           // f16 features live here first
    _Float16* Wt  = (_Float16*)(ws + 2 * SZH);       // Wt16: 9*128*128 f16
    char* p = ws + 2 * SZH + (size_t)N_MID * NH * NH * 2;
    int2* rec  = (int2*)p;                           // 12.8 MB
    int2* gbuf = (int2*)(p + (size_t)NE * 8);        // 12.8 MB
    int* bh    = (int*)(p + 2 * (size_t)NE * 8);     // NP1B*NBKT
    int* obh   = bh + NP1B * NBKT;                   // NP1B*NBKT
    int* btot  = obh + NP1B * NBKT;                  // NBKT
    int* bbase = btot + NBKT;                        // NBKT+1
    int* rp    = bbase + NBKT + 1;                   // NN+1
    float* s10 = (float*)(rp + NN + 1);
    float* o10 = s10 + NN;
    float* pmax = o10 + NN;
    float* psum = pmax + LSM_NB;
    float* cbuf = psum + LSM_NB;

    // prep: dtype conversions
    conv_x<<<(NN * NH / 8 + 255) / 256, 256, 0, stream>>>(features, xB);
    conv_w<<<(N_MID * NH * NH + 255) / 256, 256, 0, stream>>>(Ws, Wt);

    // edge sort + CSR build
    bhist_k<<<NP1B, 256, 0, stream>>>(edst, bh);
    bscan_cols<<<NBKT, 512, 0, stream>>>(bh, obh, btot);
    bscan_top<<<1, 512, 0, stream>>>(btot, bbase);
    p1_bucket<<<NP1B, 256, 0, stream>>>(esrc, edst, adj_vals, bbase, obh, gbuf);
    p2_sort<<<NBKT, 256, 0, stream>>>(gbuf, bbase, rp, rec);

    const _Float16* xin = xB;
    _Float16* xout = xA;
    for (int l = 0; l < N_MID; l++) {
        layer_fused<<<(NN + 63) / 64, 256, 0, stream>>>(xin, Wt + (size_t)l * NH * NH, rec, rp,
                                                        bs + (size_t)l * NH, xout);
        xin = xout;
        xout = (xout == xA) ? xB : xA;
    }

    dot128_f16<<<NN / 4, 256, 0, stream>>>(xin, W10, s10);
    spmm_scalar<<<(NN + 255) / 256, 256, 0, stream>>>(s10, rec, rp, b10, o10);
    lsm_max<<<LSM_NB, 256, 0, stream>>>(o10, pmax);
    lsm_sum<<<LSM_NB, 256, 0, stream>>>(o10, pmax, psum);
    lsm_fin<<<1, 256, 0, stream>>>(pmax, psum, cbuf);
    lsm_write<<<(NN + 255) / 256, 256, 0, stream>>>(o10, cbuf, out);
}

// Round 10
// 760.035 us; speedup vs baseline: 1.3879x; 1.3879x over previous
//
#include <hip/hip_runtime.h>
#include <float.h>

#define NN 100000
#define NE 1600000
#define NH 128
#define N_MID 9
#define NBKT ((NN + 255) / 256)      // 391 dst-buckets of 256 nodes
#define P1_EPB 4096                  // edges per pass-1 block
#define NP1B ((NE + P1_EPB - 1) / P1_EPB)  // 391 pass-1 blocks
#define P2_CAP 5120                  // LDS record capacity in pass 2 (avg 4092, sigma 64)

typedef _Float16 half8 __attribute__((ext_vector_type(8)));
typedef _Float16 half2v __attribute__((ext_vector_type(2)));
typedef float f32x4 __attribute__((ext_vector_type(4)));

// ---------------- dtype prep ----------------

__global__ __launch_bounds__(256) void conv_x(const float* __restrict__ in, _Float16* __restrict__ out) {
    int i = blockIdx.x * 256 + threadIdx.x;
    if (i >= NN * NH / 8) return;
    float4 v0 = ((const float4*)in)[i * 2];
    float4 v1 = ((const float4*)in)[i * 2 + 1];
    half8 o;
    o[0] = (_Float16)v0.x; o[1] = (_Float16)v0.y; o[2] = (_Float16)v0.z; o[3] = (_Float16)v0.w;
    o[4] = (_Float16)v1.x; o[5] = (_Float16)v1.y; o[6] = (_Float16)v1.z; o[7] = (_Float16)v1.w;
    ((half8*)out)[i] = o;
}

__global__ __launch_bounds__(256) void conv_w(const float* __restrict__ W, _Float16* __restrict__ Wt) {
    int i = blockIdx.x * 256 + threadIdx.x;
    if (i >= N_MID * NH * NH) return;
    int l = i / (NH * NH), rem = i % (NH * NH);
    int n = rem / NH, k = rem % NH;
    Wt[i] = (_Float16)W[l * NH * NH + k * NH + n];
}

// ---------------- edge sort: atomic-free bucket pipeline ----------------

__global__ __launch_bounds__(256) void bhist_k(const int* __restrict__ edst, int* __restrict__ bh) {
    __shared__ int hist[NBKT];
    const int tid = threadIdx.x;
    for (int i = tid; i < NBKT; i += 256) hist[i] = 0;
    __syncthreads();
    const int e0 = blockIdx.x * P1_EPB;
    const int e1 = min(e0 + P1_EPB, NE);
    for (int e = e0 + tid; e < e1; e += 256) atomicAdd(&hist[edst[e] >> 8], 1);
    __syncthreads();
    for (int i = tid; i < NBKT; i += 256) bh[blockIdx.x * NBKT + i] = hist[i];
}

__global__ __launch_bounds__(512) void bscan_cols(const int* __restrict__ bh, int* __restrict__ obh,
                                                  int* __restrict__ btot) {
    __shared__ int s[512];
    const int b = blockIdx.x, tid = threadIdx.x;
    int v = (tid < NP1B) ? bh[tid * NBKT + b] : 0;
    s[tid] = v;
    __syncthreads();
    for (int off = 1; off < 512; off <<= 1) {
        int t = (tid >= off) ? s[tid - off] : 0;
        __syncthreads();
        s[tid] += t;
        __syncthreads();
    }
    if (tid < NP1B) obh[tid * NBKT + b] = s[tid] - v;
    if (tid == NP1B - 1) btot[b] = s[tid];
}

__global__ __launch_bounds__(512) void bscan_top(const int* __restrict__ btot, int* __restrict__ bbase) {
    __shared__ int s[512];
    const int tid = threadIdx.x;
    int v = (tid < NBKT) ? btot[tid] : 0;
    s[tid] = v;
    __syncthreads();
    for (int off = 1; off < 512; off <<= 1) {
        int t = (tid >= off) ? s[tid - off] : 0;
        __syncthreads();
        s[tid] += t;
        __syncthreads();
    }
    if (tid < NBKT) bbase[tid] = s[tid] - v;
    if (tid == NBKT - 1) bbase[NBKT] = s[tid];   // == NE
}

__global__ __launch_bounds__(256) void p1_bucket(const int* __restrict__ esrc, const int* __restrict__ edst,
                                                 const float* __restrict__ av, const int* __restrict__ bbase,
                                                 const int* __restrict__ obh, int2* __restrict__ gbuf) {
    __shared__ int base[NBKT];
    __shared__ int rnk[NBKT];
    const int tid = threadIdx.x;
    for (int i = tid; i < NBKT; i += 256) {
        base[i] = bbase[i] + obh[blockIdx.x * NBKT + i];
        rnk[i] = 0;
    }
    __syncthreads();
    const int e0 = blockIdx.x * P1_EPB;
    const int e1 = min(e0 + P1_EPB, NE);
    for (int e = e0 + tid; e < e1; e += 256) {
        int d = edst[e];
        int b = d >> 8;
        int r = atomicAdd(&rnk[b], 1);
        gbuf[base[b] + r] = make_int2(esrc[e] | ((d & 255) << 24), __float_as_int(av[e]));
    }
}

__global__ __launch_bounds__(256) void p2_sort(const int2* __restrict__ gbuf, const int* __restrict__ bbase,
                                               int* __restrict__ rp, int2* __restrict__ rec) {
    __shared__ int hist[256];
    __shared__ int sc[256];
    __shared__ int offs[256];
    __shared__ int r2[256];
    __shared__ int2 buf[P2_CAP];
    const int b = blockIdx.x;
    const int tid = threadIdx.x;
    const int n0 = b * 256;
    const int e0 = bbase[b];
    const int e1 = bbase[b + 1];
    const int n = e1 - e0;
    hist[tid] = 0; r2[tid] = 0;
    __syncthreads();
    for (int i = tid; i < n; i += 256) atomicAdd(&hist[(unsigned)gbuf[e0 + i].x >> 24], 1);
    __syncthreads();
    sc[tid] = hist[tid];
    __syncthreads();
    for (int off = 1; off < 256; off <<= 1) {
        int t = (tid >= off) ? sc[tid - off] : 0;
        __syncthreads();
        sc[tid] += t;
        __syncthreads();
    }
    offs[tid] = sc[tid] - hist[tid];
    __syncthreads();
    if (n0 + tid < NN) rp[n0 + tid] = e0 + offs[tid];
    if (b == NBKT - 1 && tid == 0) rp[NN] = e1;
    if (n <= P2_CAP) {
        for (int i = tid; i < n; i += 256) {
            int2 rv = gbuf[e0 + i];
            int dl = (unsigned)rv.x >> 24;
            int p = offs[dl] + atomicAdd(&r2[dl], 1);
            buf[p] = make_int2(rv.x & 0x00FFFFFF, rv.y);
        }
        __syncthreads();
        for (int i = tid; i < n; i += 256) rec[e0 + i] = buf[i];
    } else {
        for (int i = tid; i < n; i += 256) {
            int2 rv = gbuf[e0 + i];
            int dl = (unsigned)rv.x >> 24;
            int p = offs[dl] + atomicAdd(&r2[dl], 1);
            rec[e0 + p] = make_int2(rv.x & 0x00FFFFFF, rv.y);
        }
    }
}

// ---------------- GEMM: S = X @ W  (f16 in/out, f32 acc, MFMA, Wt in LDS) ----------------

#define WLD 136

__global__ __launch_bounds__(256) void gemm_mfma(const _Float16* __restrict__ X, const _Float16* __restrict__ Wt,
                                                 _Float16* __restrict__ S) {
    __shared__ _Float16 wsh[128 * WLD];
    const int tid = threadIdx.x;
    // stage Wt: 16384 halves = 2048 half8-chunks, coalesced
    for (int c = tid; c < 2048; c += 256) {
        int row = c >> 4, col = c & 15;
        *(half8*)&wsh[row * WLD + col * 8] = *(const half8*)&Wt[row * 128 + col * 8];
    }

    const int wid = threadIdx.x >> 6;
    const int lane = threadIdx.x & 63;
    const int r = lane & 15, kb = lane >> 4;
    const int row0 = blockIdx.x * 64 + wid * 16;
    int arow = row0 + r;
    if (arow >= NN) arow = NN - 1;
    const _Float16* xp = X + (size_t)arow * NH + kb * 8;
    half8 a0 = *(const half8*)(xp);
    half8 a1 = *(const half8*)(xp + 32);
    half8 a2 = *(const half8*)(xp + 64);
    half8 a3 = *(const half8*)(xp + 96);
    f32x4 acc[8];
#pragma unroll
    for (int t = 0; t < 8; t++) acc[t] = (f32x4){0.f, 0.f, 0.f, 0.f};
    __syncthreads();
#pragma unroll
    for (int t = 0; t < 8; t++) {
        const _Float16* wp = wsh + (16 * t + r) * WLD + kb * 8;
        half8 b0 = *(const half8*)(wp);
        half8 b1 = *(const half8*)(wp + 32);
        half8 b2 = *(const half8*)(wp + 64);
        half8 b3 = *(const half8*)(wp + 96);
        acc[t] = __builtin_amdgcn_mfma_f32_16x16x32_f16(a0, b0, acc[t], 0, 0, 0);
        acc[t] = __builtin_amdgcn_mfma_f32_16x16x32_f16(a1, b1, acc[t], 0, 0, 0);
        acc[t] = __builtin_amdgcn_mfma_f32_16x16x32_f16(a2, b2, acc[t], 0, 0, 0);
        acc[t] = __builtin_amdgcn_mfma_f32_16x16x32_f16(a3, b3, acc[t], 0, 0, 0);
    }
    const int orow = row0 + kb * 4;
#pragma unroll
    for (int j = 0; j < 4; j++) {
        if (orow + j < NN) {
            _Float16* sp = S + (size_t)(orow + j) * NH + r;
#pragma unroll
            for (int t = 0; t < 8; t++) sp[16 * t] = (_Float16)acc[t][j];
        }
    }
}

// ---------------- SPMM (CSR) + bias + relu, f16 rows, 4 nodes per wave ----------------

__global__ __launch_bounds__(256) void spmm_f16(const _Float16* __restrict__ S, const int2* __restrict__ rec,
                                                const int* __restrict__ rp, const float* __restrict__ bias,
                                                _Float16* __restrict__ Xo) {
    const int wv = blockIdx.x * 4 + (threadIdx.x >> 6);
    const int node0 = wv * 4;
    if (node0 >= NN) return;
    const int lane = threadIdx.x & 63;
    const int g = lane >> 4;        // edge group 0..3 (stride 4 over node's edges)
    const int c = lane & 15;        // cols 8c..8c+7
    const int nEnd = min(node0 + 4, NN);
    const float4 b0 = *(const float4*)&bias[c * 8];
    const float4 b1 = *(const float4*)&bias[c * 8 + 4];

    int beg = rp[node0];
    for (int node = node0; node < nEnd; node++) {
        int end = rp[node + 1];
        float acc[8] = {0.f, 0.f, 0.f, 0.f, 0.f, 0.f, 0.f, 0.f};
        float acc2[8] = {0.f, 0.f, 0.f, 0.f, 0.f, 0.f, 0.f, 0.f};
        int e = beg + g;
        int2 n1 = make_int2(0, 0), n2 = make_int2(0, 0);
        if (e + 4 < end) { n1 = rec[e]; n2 = rec[e + 4]; }
        for (; e + 4 < end; e += 8) {
            int2 rv1 = n1, rv2 = n2;
            if (e + 12 < end) { n1 = rec[e + 8]; n2 = rec[e + 12]; }   // prefetch next pair
            half8 r1 = *(const half8*)&S[(size_t)rv1.x * NH + c * 8];
            half8 r2 = *(const half8*)&S[(size_t)rv2.x * NH + c * 8];
            float v1 = __int_as_float(rv1.y);
            float v2 = __int_as_float(rv2.y);
#pragma unroll
            for (int j = 0; j < 8; j++) {
                acc[j]  = fmaf(v1, (float)r1[j], acc[j]);
                acc2[j] = fmaf(v2, (float)r2[j], acc2[j]);
            }
        }
        if (e < end) {
            int2 rv = rec[e];
            float v = __int_as_float(rv.y);
            half8 r1 = *(const half8*)&S[(size_t)rv.x * NH + c * 8];
#pragma unroll
            for (int j = 0; j < 8; j++) acc[j] = fmaf(v, (float)r1[j], acc[j]);
        }
#pragma unroll
        for (int j = 0; j < 8; j++) {
            acc[j] += acc2[j];
            acc[j] += __shfl_xor(acc[j], 16, 64);
            acc[j] += __shfl_xor(acc[j], 32, 64);
        }
        if (g == 0) {
            half8 o;
            o[0] = (_Float16)fmaxf(acc[0] + b0.x, 0.f);
            o[1] = (_Float16)fmaxf(acc[1] + b0.y, 0.f);
            o[2] = (_Float16)fmaxf(acc[2] + b0.z, 0.f);
            o[3] = (_Float16)fmaxf(acc[3] + b0.w, 0.f);
            o[4] = (_Float16)fmaxf(acc[4] + b1.x, 0.f);
            o[5] = (_Float16)fmaxf(acc[5] + b1.y, 0.f);
            o[6] = (_Float16)fmaxf(acc[6] + b1.z, 0.f);
            o[7] = (_Float16)fmaxf(acc[7] + b1.w, 0.f);
            *(half8*)&Xo[(size_t)node * NH + c * 8] = o;
        }
        beg = end;
    }
}

// ---------------- layer 10 ----------------

__global__ __launch_bounds__(256) void dot128_f16(const _Float16* __restrict__ X, const float* __restrict__ w,
                                                  float* __restrict__ s10) {
    int node = blockIdx.x * 4 + (threadIdx.x >> 6);
    if (node >= NN) return;
    int lane = threadIdx.x & 63;
    half2v xv = *(const half2v*)&X[(size_t)node * NH + lane * 2];
    float2 wv = *(const float2*)&w[lane * 2];
    float p = (float)xv[0] * wv.x + (float)xv[1] * wv.y;
#pragma unroll
    for (int off = 32; off; off >>= 1) p += __shfl_down(p, off, 64);
    if (lane == 0) s10[node] = p;
}

__global__ __launch_bounds__(256) void spmm_scalar(const float* __restrict__ s10, const int2* __restrict__ rec,
                                                   const int* __restrict__ rp, const float* __restrict__ b10,
                                                   float* __restrict__ o10) {
    int node = blockIdx.x * 256 + threadIdx.x;
    if (node >= NN) return;
    int beg = rp[node], end = rp[node + 1];
    float a = 0.f;
    for (int e = beg; e < end; e++) {
        int2 r = rec[e];
        a = fmaf(__int_as_float(r.y), s10[r.x], a);
    }
    o10[node] = a + b10[0];
}

// ---------------- log_softmax ----------------

#define LSM_NB 240

__global__ __launch_bounds__(256) void lsm_max(const float* __restrict__ v, float* __restrict__ pmax) {
    __shared__ float s[256];
    float m = -FLT_MAX;
    for (int i = blockIdx.x * 256 + threadIdx.x; i < NN; i += LSM_NB * 256) m = fmaxf(m, v[i]);
    s[threadIdx.x] = m;
    __syncthreads();
    for (int off = 128; off; off >>= 1) {
        if (threadIdx.x < off) s[threadIdx.x] = fmaxf(s[threadIdx.x], s[threadIdx.x + off]);
        __syncthreads();
    }
    if (threadIdx.x == 0) pmax[blockIdx.x] = s[0];
}

__global__ __launch_bounds__(256) void lsm_sum(const float* __restrict__ v, const float* __restrict__ pmax,
                                               float* __restrict__ psum) {
    __shared__ float s[256];
    float m = -FLT_MAX;
    if (threadIdx.x < LSM_NB) m = pmax[threadIdx.x];
    s[threadIdx.x] = m;
    __syncthreads();
    for (int off = 128; off; off >>= 1) {
        if (threadIdx.x < off) s[threadIdx.x] = fmaxf(s[threadIdx.x], s[threadIdx.x + off]);
        __syncthreads();
    }
    float gm = s[0];
    __syncthreads();
    float sum = 0.f;
    for (int i = blockIdx.x * 256 + threadIdx.x; i < NN; i += LSM_NB * 256) sum += expf(v[i] - gm);
    s[threadIdx.x] = sum;
    __syncthreads();
    for (int off = 128; off; off >>= 1) {
        if (threadIdx.x < off) s[threadIdx.x] += s[threadIdx.x + off];
        __syncthreads();
    }
    if (threadIdx.x == 0) psum[blockIdx.x] = s[0];
}

__global__ __launch_bounds__(256) void lsm_fin(const float* __restrict__ pmax, const float* __restrict__ psum,
                                               float* __restrict__ c) {
    __shared__ float s[256];
    float m = -FLT_MAX, sum = 0.f;
    if (threadIdx.x < LSM_NB) { m = pmax[threadIdx.x]; sum = psum[threadIdx.x]; }
    s[threadIdx.x] = m;
    __syncthreads();
    for (int off = 128; off; off >>= 1) {
        if (threadIdx.x < off) s[threadIdx.x] = fmaxf(s[threadIdx.x], s[threadIdx.x + off]);
        __syncthreads();
    }
    float gm = s[0];
    __syncthreads();
    s[threadIdx.x] = sum;
    __syncthreads();
    for (int off = 128; off; off >>= 1) {
        if (threadIdx.x < off) s[threadIdx.x] += s[threadIdx.x + off];
        __syncthreads();
    }
    if (threadIdx.x == 0) c[0] = gm + logf(s[0]);
}

__global__ __launch_bounds__(256) void lsm_write(const float* __restrict__ o10, const float* __restrict__ c,
                                                 float* __restrict__ out) {
    int i = blockIdx.x * 256 + threadIdx.x;
    if (i < NN) out[i] = o10[i] - c[0];
}

// ---------------- launch ----------------

extern "C" void kernel_launch(void* const* d_in, const int* in_sizes, int n_in,
                              void* d_out, int out_size, void* d_ws, size_t ws_size,
                              hipStream_t stream) {
    const float* features = (const float*)d_in[0];
    const float* adj_vals = (const float*)d_in[1];
    const float* Ws       = (const float*)d_in[2];
    const float* bs       = (const float*)d_in[3];
    const float* W10      = (const float*)d_in[4];
    const float* b10      = (const float*)d_in[5];
    const int*   esrc     = (const int*)d_in[6];
    const int*   edst     = (const int*)d_in[7];
    float* out = (float*)d_out;

    char* ws = (char*)d_ws;
    const size_t SZH = (size_t)NN * NH * 2;          // 25.6 MB per f16 buffer
    _Float16* S_h = (_Float16*)(ws);
    _Float16* xA  = (_Float16*)(ws + SZH);
    _Float16* xB  = (_Float16*)(ws + 2 * SZH);       // f16 features live here first
    _Float16* Wt  = (_Float16*)(ws + 3 * SZH);
    char* p = ws + 3 * SZH + (size_t)N_MID * NH * NH * 2;
    int2* rec  = (int2*)p;                           // 12.8 MB
    int2* gbuf = (int2*)(p + (size_t)NE * 8);        // 12.8 MB
    int* bh    = (int*)(p + 2 * (size_t)NE * 8);     // NP1B*NBKT
    int* obh   = bh + NP1B * NBKT;                   // NP1B*NBKT
    int* btot  = obh + NP1B * NBKT;                  // NBKT
    int* bbase = btot + NBKT;                        // NBKT+1
    int* rp    = bbase + NBKT + 1;                   // NN+1
    float* s10 = (float*)(rp + NN + 1);
    float* o10 = s10 + NN;
    float* pmax = o10 + NN;
    float* psum = pmax + LSM_NB;
    float* cbuf = psum + LSM_NB;

    // prep: dtype conversions
    conv_x<<<(NN * NH / 8 + 255) / 256, 256, 0, stream>>>(features, xB);
    conv_w<<<(N_MID * NH * NH + 255) / 256, 256, 0, stream>>>(Ws, Wt);

    // edge sort + CSR build
    bhist_k<<<NP1B, 256, 0, stream>>>(edst, bh);
    bscan_cols<<<NBKT, 512, 0, stream>>>(bh, obh, btot);
    bscan_top<<<1, 512, 0, stream>>>(btot, bbase);
    p1_bucket<<<NP1B, 256, 0, stream>>>(esrc, edst, adj_vals, bbase, obh, gbuf);
    p2_sort<<<NBKT, 256, 0, stream>>>(gbuf, bbase, rp, rec);

    const _Float16* xin = xB;
    _Float16* xout = xA;
    for (int l = 0; l < N_MID; l++) {
        gemm_mfma<<<(NN + 63) / 64, 256, 0, stream>>>(xin, Wt + (size_t)l * NH * NH, S_h);
        spmm_f16<<<(NN + 15) / 16, 256, 0, stream>>>(S_h, rec, rp, bs + (size_t)l * NH, xout);
        xin = xout;
        xout = (xout == xA) ? xB : xA;
    }

    dot128_f16<<<NN / 4, 256, 0, stream>>>(xin, W10, s10);
    spmm_scalar<<<(NN + 255) / 256, 256, 0, stream>>>(s10, rec, rp, b10, o10);
    lsm_max<<<LSM_NB, 256, 0, stream>>>(o10, pmax);
    lsm_sum<<<LSM_NB, 256, 0, stream>>>(o10, pmax, psum);
    lsm_fin<<<1, 256, 0, stream>>>(pmax, psum, cbuf);
    lsm_write<<<(NN + 255) / 256, 256, 0, stream>>>(o10, cbuf, out);
}

// Round 11
// 745.665 us; speedup vs baseline: 1.4147x; 1.0193x over previous
//
#include <hip/hip_runtime.h>
#include <float.h>

#define NN 100000
#define NE 1600000
#define NH 128
#define N_MID 9
#define NBKT ((NN + 255) / 256)      // 391 dst-buckets of 256 nodes
#define P1_EPB 4096                  // edges per pass-1 block
#define NP1B ((NE + P1_EPB - 1) / P1_EPB)  // 391 pass-1 blocks
#define P2_CAP 5120                  // LDS record capacity in pass 2 (avg 4092, sigma 64)

typedef _Float16 half8 __attribute__((ext_vector_type(8)));
typedef float f32x4 __attribute__((ext_vector_type(4)));

// ---------------- dtype prep (weights only; features handled by f32 gemm) ----------------

__global__ __launch_bounds__(256) void conv_w(const float* __restrict__ W, _Float16* __restrict__ Wt) {
    int i = blockIdx.x * 256 + threadIdx.x;
    if (i >= N_MID * NH * NH) return;
    int l = i / (NH * NH), rem = i % (NH * NH);
    int n = rem / NH, k = rem % NH;
    Wt[i] = (_Float16)W[l * NH * NH + k * NH + n];
}

// ---------------- edge sort: atomic-free bucket pipeline ----------------

__global__ __launch_bounds__(256) void bhist_k(const int* __restrict__ edst, int* __restrict__ bh) {
    __shared__ int hist[NBKT];
    const int tid = threadIdx.x;
    for (int i = tid; i < NBKT; i += 256) hist[i] = 0;
    __syncthreads();
    const int e0 = blockIdx.x * P1_EPB;
    const int e1 = min(e0 + P1_EPB, NE);
    for (int e = e0 + tid; e < e1; e += 256) atomicAdd(&hist[edst[e] >> 8], 1);
    __syncthreads();
    for (int i = tid; i < NBKT; i += 256) bh[blockIdx.x * NBKT + i] = hist[i];
}

__global__ __launch_bounds__(512) void bscan_cols(const int* __restrict__ bh, int* __restrict__ obh,
                                                  int* __restrict__ btot) {
    __shared__ int s[512];
    const int b = blockIdx.x, tid = threadIdx.x;
    int v = (tid < NP1B) ? bh[tid * NBKT + b] : 0;
    s[tid] = v;
    __syncthreads();
    for (int off = 1; off < 512; off <<= 1) {
        int t = (tid >= off) ? s[tid - off] : 0;
        __syncthreads();
        s[tid] += t;
        __syncthreads();
    }
    if (tid < NP1B) obh[tid * NBKT + b] = s[tid] - v;
    if (tid == NP1B - 1) btot[b] = s[tid];
}

__global__ __launch_bounds__(512) void bscan_top(const int* __restrict__ btot, int* __restrict__ bbase) {
    __shared__ int s[512];
    const int tid = threadIdx.x;
    int v = (tid < NBKT) ? btot[tid] : 0;
    s[tid] = v;
    __syncthreads();
    for (int off = 1; off < 512; off <<= 1) {
        int t = (tid >= off) ? s[tid - off] : 0;
        __syncthreads();
        s[tid] += t;
        __syncthreads();
    }
    if (tid < NBKT) bbase[tid] = s[tid] - v;
    if (tid == NBKT - 1) bbase[NBKT] = s[tid];   // == NE
}

__global__ __launch_bounds__(256) void p1_bucket(const int* __restrict__ esrc, const int* __restrict__ edst,
                                                 const float* __restrict__ av, const int* __restrict__ bbase,
                                                 const int* __restrict__ obh, int2* __restrict__ gbuf) {
    __shared__ int base[NBKT];
    __shared__ int rnk[NBKT];
    const int tid = threadIdx.x;
    for (int i = tid; i < NBKT; i += 256) {
        base[i] = bbase[i] + obh[blockIdx.x * NBKT + i];
        rnk[i] = 0;
    }
    __syncthreads();
    const int e0 = blockIdx.x * P1_EPB;
    const int e1 = min(e0 + P1_EPB, NE);
    for (int e = e0 + tid; e < e1; e += 256) {
        int d = edst[e];
        int b = d >> 8;
        int r = atomicAdd(&rnk[b], 1);
        gbuf[base[b] + r] = make_int2(esrc[e] | ((d & 255) << 24), __float_as_int(av[e]));
    }
}

__global__ __launch_bounds__(256) void p2_sort(const int2* __restrict__ gbuf, const int* __restrict__ bbase,
                                               int* __restrict__ rp, int2* __restrict__ rec) {
    __shared__ int hist[256];
    __shared__ int sc[256];
    __shared__ int offs[256];
    __shared__ int r2[256];
    __shared__ int2 buf[P2_CAP];
    const int b = blockIdx.x;
    const int tid = threadIdx.x;
    const int n0 = b * 256;
    const int e0 = bbase[b];
    const int e1 = bbase[b + 1];
    const int n = e1 - e0;
    hist[tid] = 0; r2[tid] = 0;
    __syncthreads();
    for (int i = tid; i < n; i += 256) atomicAdd(&hist[(unsigned)gbuf[e0 + i].x >> 24], 1);
    __syncthreads();
    sc[tid] = hist[tid];
    __syncthreads();
    for (int off = 1; off < 256; off <<= 1) {
        int t = (tid >= off) ? sc[tid - off] : 0;
        __syncthreads();
        sc[tid] += t;
        __syncthreads();
    }
    offs[tid] = sc[tid] - hist[tid];
    __syncthreads();
    if (n0 + tid < NN) rp[n0 + tid] = e0 + offs[tid];
    if (b == NBKT - 1 && tid == 0) rp[NN] = e1;
    if (n <= P2_CAP) {
        for (int i = tid; i < n; i += 256) {
            int2 rv = gbuf[e0 + i];
            int dl = (unsigned)rv.x >> 24;
            int p = offs[dl] + atomicAdd(&r2[dl], 1);
            buf[p] = make_int2(rv.x & 0x00FFFFFF, rv.y);
        }
        __syncthreads();
        for (int i = tid; i < n; i += 256) rec[e0 + i] = buf[i];
    } else {
        for (int i = tid; i < n; i += 256) {
            int2 rv = gbuf[e0 + i];
            int dl = (unsigned)rv.x >> 24;
            int p = offs[dl] + atomicAdd(&r2[dl], 1);
            rec[e0 + p] = make_int2(rv.x & 0x00FFFFFF, rv.y);
        }
    }
}

// ---------------- GEMM: S = X @ W  (MFMA, Wt in LDS) ----------------

#define WLD 136

__device__ __forceinline__ void gemm_core(half8 a0, half8 a1, half8 a2, half8 a3,
                                          const _Float16* wsh, int r, int kb,
                                          int row0, _Float16* __restrict__ S) {
    f32x4 acc[8];
#pragma unroll
    for (int t = 0; t < 8; t++) acc[t] = (f32x4){0.f, 0.f, 0.f, 0.f};
#pragma unroll
    for (int t = 0; t < 8; t++) {
        const _Float16* wp = wsh + (16 * t + r) * WLD + kb * 8;
        half8 b0 = *(const half8*)(wp);
        half8 b1 = *(const half8*)(wp + 32);
        half8 b2 = *(const half8*)(wp + 64);
        half8 b3 = *(const half8*)(wp + 96);
        acc[t] = __builtin_amdgcn_mfma_f32_16x16x32_f16(a0, b0, acc[t], 0, 0, 0);
        acc[t] = __builtin_amdgcn_mfma_f32_16x16x32_f16(a1, b1, acc[t], 0, 0, 0);
        acc[t] = __builtin_amdgcn_mfma_f32_16x16x32_f16(a2, b2, acc[t], 0, 0, 0);
        acc[t] = __builtin_amdgcn_mfma_f32_16x16x32_f16(a3, b3, acc[t], 0, 0, 0);
    }
    const int orow = row0 + kb * 4;
#pragma unroll
    for (int j = 0; j < 4; j++) {
        if (orow + j < NN) {
            _Float16* sp = S + (size_t)(orow + j) * NH + r;
#pragma unroll
            for (int t = 0; t < 8; t++) sp[16 * t] = (_Float16)acc[t][j];
        }
    }
}

__global__ __launch_bounds__(256) void gemm_mfma(const _Float16* __restrict__ X, const _Float16* __restrict__ Wt,
                                                 _Float16* __restrict__ S) {
    __shared__ _Float16 wsh[128 * WLD];
    const int tid = threadIdx.x;
    for (int c = tid; c < 2048; c += 256) {
        int row = c >> 4, col = c & 15;
        *(half8*)&wsh[row * WLD + col * 8] = *(const half8*)&Wt[row * 128 + col * 8];
    }
    const int wid = tid >> 6;
    const int lane = tid & 63;
    const int r = lane & 15, kb = lane >> 4;
    const int row0 = blockIdx.x * 64 + wid * 16;
    int arow = row0 + r;
    if (arow >= NN) arow = NN - 1;
    const _Float16* xp = X + (size_t)arow * NH + kb * 8;
    half8 a0 = *(const half8*)(xp);
    half8 a1 = *(const half8*)(xp + 32);
    half8 a2 = *(const half8*)(xp + 64);
    half8 a3 = *(const half8*)(xp + 96);
    __syncthreads();
    gemm_core(a0, a1, a2, a3, wsh, r, kb, row0, S);
}

// layer-0 variant: reads f32 features directly (no conv_x pass)
__global__ __launch_bounds__(256) void gemm_mfma_f32(const float* __restrict__ X, const _Float16* __restrict__ Wt,
                                                     _Float16* __restrict__ S) {
    __shared__ _Float16 wsh[128 * WLD];
    const int tid = threadIdx.x;
    for (int c = tid; c < 2048; c += 256) {
        int row = c >> 4, col = c & 15;
        *(half8*)&wsh[row * WLD + col * 8] = *(const half8*)&Wt[row * 128 + col * 8];
    }
    const int wid = tid >> 6;
    const int lane = tid & 63;
    const int r = lane & 15, kb = lane >> 4;
    const int row0 = blockIdx.x * 64 + wid * 16;
    int arow = row0 + r;
    if (arow >= NN) arow = NN - 1;
    const float* xp = X + (size_t)arow * NH + kb * 8;
    half8 a[4];
#pragma unroll
    for (int s = 0; s < 4; s++) {
        float4 f0 = *(const float4*)(xp + 32 * s);
        float4 f1 = *(const float4*)(xp + 32 * s + 4);
        a[s][0] = (_Float16)f0.x; a[s][1] = (_Float16)f0.y;
        a[s][2] = (_Float16)f0.z; a[s][3] = (_Float16)f0.w;
        a[s][4] = (_Float16)f1.x; a[s][5] = (_Float16)f1.y;
        a[s][6] = (_Float16)f1.z; a[s][7] = (_Float16)f1.w;
    }
    __syncthreads();
    gemm_core(a[0], a[1], a[2], a[3], wsh, r, kb, row0, S);
}

// ---------------- SPMM (CSR) + bias + relu, 4 nodes/wave; optional fused W10 dot ----------------

__global__ __launch_bounds__(256) void spmm_f16(const _Float16* __restrict__ S, const int2* __restrict__ rec,
                                                const int* __restrict__ rp, const float* __restrict__ bias,
                                                _Float16* __restrict__ Xo, const float* __restrict__ w10,
                                                float* __restrict__ s10, int fuseDot) {
    const int wv = blockIdx.x * 4 + (threadIdx.x >> 6);
    const int node0 = wv * 4;
    if (node0 >= NN) return;
    const int lane = threadIdx.x & 63;
    const int g = lane >> 4;        // edge group 0..3 (stride 4 over node's edges)
    const int c = lane & 15;        // cols 8c..8c+7
    const int nEnd = min(node0 + 4, NN);
    const float4 b0 = *(const float4*)&bias[c * 8];
    const float4 b1 = *(const float4*)&bias[c * 8 + 4];

    int beg = rp[node0];
    for (int node = node0; node < nEnd; node++) {
        int end = rp[node + 1];
        float acc[8] = {0.f, 0.f, 0.f, 0.f, 0.f, 0.f, 0.f, 0.f};
        float acc2[8] = {0.f, 0.f, 0.f, 0.f, 0.f, 0.f, 0.f, 0.f};
        int e = beg + g;
        int2 n1 = make_int2(0, 0), n2 = make_int2(0, 0);
        if (e + 4 < end) { n1 = rec[e]; n2 = rec[e + 4]; }
        for (; e + 4 < end; e += 8) {
            int2 rv1 = n1, rv2 = n2;
            if (e + 12 < end) { n1 = rec[e + 8]; n2 = rec[e + 12]; }   // prefetch next pair
            half8 r1 = *(const half8*)&S[(size_t)rv1.x * NH + c * 8];
            half8 r2 = *(const half8*)&S[(size_t)rv2.x * NH + c * 8];
            float v1 = __int_as_float(rv1.y);
            float v2 = __int_as_float(rv2.y);
#pragma unroll
            for (int j = 0; j < 8; j++) {
                acc[j]  = fmaf(v1, (float)r1[j], acc[j]);
                acc2[j] = fmaf(v2, (float)r2[j], acc2[j]);
            }
        }
        if (e < end) {
            int2 rv = rec[e];
            float v = __int_as_float(rv.y);
            half8 r1 = *(const half8*)&S[(size_t)rv.x * NH + c * 8];
#pragma unroll
            for (int j = 0; j < 8; j++) acc[j] = fmaf(v, (float)r1[j], acc[j]);
        }
#pragma unroll
        for (int j = 0; j < 8; j++) {
            acc[j] += acc2[j];
            acc[j] += __shfl_xor(acc[j], 16, 64);
            acc[j] += __shfl_xor(acc[j], 32, 64);
        }
        if (g == 0) {
            half8 o;
            o[0] = (_Float16)fmaxf(acc[0] + b0.x, 0.f);
            o[1] = (_Float16)fmaxf(acc[1] + b0.y, 0.f);
            o[2] = (_Float16)fmaxf(acc[2] + b0.z, 0.f);
            o[3] = (_Float16)fmaxf(acc[3] + b0.w, 0.f);
            o[4] = (_Float16)fmaxf(acc[4] + b1.x, 0.f);
            o[5] = (_Float16)fmaxf(acc[5] + b1.y, 0.f);
            o[6] = (_Float16)fmaxf(acc[6] + b1.z, 0.f);
            o[7] = (_Float16)fmaxf(acc[7] + b1.w, 0.f);
            if (!fuseDot) {
                *(half8*)&Xo[(size_t)node * NH + c * 8] = o;
            } else {
                // layer-9: x @ W10 directly (lanes 0..15 hold the row); skip Xo write
                float4 wa = *(const float4*)&w10[c * 8];
                float4 wb = *(const float4*)&w10[c * 8 + 4];
                float p = (float)o[0] * wa.x + (float)o[1] * wa.y + (float)o[2] * wa.z + (float)o[3] * wa.w
                        + (float)o[4] * wb.x + (float)o[5] * wb.y + (float)o[6] * wb.z + (float)o[7] * wb.w;
#pragma unroll
                for (int off = 8; off; off >>= 1) p += __shfl_xor(p, off, 64);
                if (c == 0) s10[node] = p;
            }
        }
        beg = end;
    }
}

// ---------------- layer 10 spmm + log_softmax ----------------

__global__ __launch_bounds__(256) void spmm_scalar(const float* __restrict__ s10, const int2* __restrict__ rec,
                                                   const int* __restrict__ rp, const float* __restrict__ b10,
                                                   float* __restrict__ o10) {
    int node = blockIdx.x * 256 + threadIdx.x;
    if (node >= NN) return;
    int beg = rp[node], end = rp[node + 1];
    float a = 0.f;
    for (int e = beg; e < end; e++) {
        int2 r = rec[e];
        a = fmaf(__int_as_float(r.y), s10[r.x], a);
    }
    o10[node] = a + b10[0];
}

#define LSM_NB 240

__global__ __launch_bounds__(256) void lsm_max(const float* __restrict__ v, float* __restrict__ pmax) {
    __shared__ float s[256];
    float m = -FLT_MAX;
    for (int i = blockIdx.x * 256 + threadIdx.x; i < NN; i += LSM_NB * 256) m = fmaxf(m, v[i]);
    s[threadIdx.x] = m;
    __syncthreads();
    for (int off = 128; off; off >>= 1) {
        if (threadIdx.x < off) s[threadIdx.x] = fmaxf(s[threadIdx.x], s[threadIdx.x + off]);
        __syncthreads();
    }
    if (threadIdx.x == 0) pmax[blockIdx.x] = s[0];
}

__global__ __launch_bounds__(256) void lsm_sum(const float* __restrict__ v, const float* __restrict__ pmax,
                                               float* __restrict__ psum) {
    __shared__ float s[256];
    float m = -FLT_MAX;
    if (threadIdx.x < LSM_NB) m = pmax[threadIdx.x];
    s[threadIdx.x] = m;
    __syncthreads();
    for (int off = 128; off; off >>= 1) {
        if (threadIdx.x < off) s[threadIdx.x] = fmaxf(s[threadIdx.x], s[threadIdx.x + off]);
        __syncthreads();
    }
    float gm = s[0];
    __syncthreads();
    float sum = 0.f;
    for (int i = blockIdx.x * 256 + threadIdx.x; i < NN; i += LSM_NB * 256) sum += expf(v[i] - gm);
    s[threadIdx.x] = sum;
    __syncthreads();
    for (int off = 128; off; off >>= 1) {
        if (threadIdx.x < off) s[threadIdx.x] += s[threadIdx.x + off];
        __syncthreads();
    }
    if (threadIdx.x == 0) psum[blockIdx.x] = s[0];
}

__global__ __launch_bounds__(256) void lsm_fin(const float* __restrict__ pmax, const float* __restrict__ psum,
                                               float* __restrict__ c) {
    __shared__ float s[256];
    float m = -FLT_MAX, sum = 0.f;
    if (threadIdx.x < LSM_NB) { m = pmax[threadIdx.x]; sum = psum[threadIdx.x]; }
    s[threadIdx.x] = m;
    __syncthreads();
    for (int off = 128; off; off >>= 1) {
        if (threadIdx.x < off) s[threadIdx.x] = fmaxf(s[threadIdx.x], s[threadIdx.x + off]);
        __syncthreads();
    }
    float gm = s[0];
    __syncthreads();
    s[threadIdx.x] = sum;
    __syncthreads();
    for (int off = 128; off; off >>= 1) {
        if (threadIdx.x < off) s[threadIdx.x] += s[threadIdx.x + off];
        __syncthreads();
    }
    if (threadIdx.x == 0) c[0] = gm + logf(s[0]);
}

__global__ __launch_bounds__(256) void lsm_write(const float* __restrict__ o10, const float* __restrict__ c,
                                                 float* __restrict__ out) {
    int i = blockIdx.x * 256 + threadIdx.x;
    if (i < NN) out[i] = o10[i] - c[0];
}

// ---------------- launch ----------------

extern "C" void kernel_launch(void* const* d_in, const int* in_sizes, int n_in,
                              void* d_out, int out_size, void* d_ws, size_t ws_size,
                              hipStream_t stream) {
    const float* features = (const float*)d_in[0];
    const float* adj_vals = (const float*)d_in[1];
    const float* Ws       = (const float*)d_in[2];
    const float* bs       = (const float*)d_in[3];
    const float* W10      = (const float*)d_in[4];
    const float* b10      = (const float*)d_in[5];
    const int*   esrc     = (const int*)d_in[6];
    const int*   edst     = (const int*)d_in[7];
    float* out = (float*)d_out;

    char* ws = (char*)d_ws;
    const size_t SZH = (size_t)NN * NH * 2;          // 25.6 MB per f16 buffer
    _Float16* S_h = (_Float16*)(ws);
    _Float16* xA  = (_Float16*)(ws + SZH);
    _Float16* xB  = (_Float16*)(ws + 2 * SZH);
    _Float16* Wt  = (_Float16*)(ws + 3 * SZH);
    char* p = ws + 3 * SZH + (size_t)N_MID * NH * NH * 2;
    int2* rec  = (int2*)p;                           // 12.8 MB
    int2* gbuf = (int2*)(p + (size_t)NE * 8);        // 12.8 MB
    int* bh    = (int*)(p + 2 * (size_t)NE * 8);     // NP1B*NBKT
    int* obh   = bh + NP1B * NBKT;                   // NP1B*NBKT
    int* btot  = obh + NP1B * NBKT;                  // NBKT
    int* bbase = btot + NBKT;                        // NBKT+1
    int* rp    = bbase + NBKT + 1;                   // NN+1
    float* s10 = (float*)(rp + NN + 1);
    float* o10 = s10 + NN;
    float* pmax = o10 + NN;
    float* psum = pmax + LSM_NB;
    float* cbuf = psum + LSM_NB;

    // prep: weight conversion
    conv_w<<<(N_MID * NH * NH + 255) / 256, 256, 0, stream>>>(Ws, Wt);

    // edge sort + CSR build
    bhist_k<<<NP1B, 256, 0, stream>>>(edst, bh);
    bscan_cols<<<NBKT, 512, 0, stream>>>(bh, obh, btot);
    bscan_top<<<1, 512, 0, stream>>>(btot, bbase);
    p1_bucket<<<NP1B, 256, 0, stream>>>(esrc, edst, adj_vals, bbase, obh, gbuf);
    p2_sort<<<NBKT, 256, 0, stream>>>(gbuf, bbase, rp, rec);

    // layer 0: f32 features -> gemm -> spmm
    gemm_mfma_f32<<<(NN + 63) / 64, 256, 0, stream>>>(features, Wt, S_h);
    spmm_f16<<<(NN + 15) / 16, 256, 0, stream>>>(S_h, rec, rp, bs, xA, nullptr, nullptr, 0);

    const _Float16* xin = xA;
    _Float16* xout = xB;
    for (int l = 1; l < N_MID; l++) {
        gemm_mfma<<<(NN + 63) / 64, 256, 0, stream>>>(xin, Wt + (size_t)l * NH * NH, S_h);
        int fuse = (l == N_MID - 1) ? 1 : 0;
        spmm_f16<<<(NN + 15) / 16, 256, 0, stream>>>(S_h, rec, rp, bs + (size_t)l * NH, xout, W10, s10, fuse);
        xin = xout;
        xout = (xout == xA) ? xB : xA;
    }

    spmm_scalar<<<(NN + 255) / 256, 256, 0, stream>>>(s10, rec, rp, b10, o10);
    lsm_max<<<LSM_NB, 256, 0, stream>>>(o10, pmax);
    lsm_sum<<<LSM_NB, 256, 0, stream>>>(o10, pmax, psum);
    lsm_fin<<<1, 256, 0, stream>>>(pmax, psum, cbuf);
    lsm_write<<<(NN + 255) / 256, 256, 0, stream>>>(o10, cbuf, out);
}